// Round 1
// baseline (161.136 us; speedup 1.0000x reference)
//
#include <hip/hip_runtime.h>
#include <math.h>

#define NB 8192
#define ND 512
#define NATTR 4
#define NPROTO 16
#define TINV 14.285714285714286f   // 1/0.07

// ---------------- K1: normalize rows + segment sums + code + valid list ----
__global__ __launch_bounds__(512) void k_norm_seg(
    const float* __restrict__ z, const float* __restrict__ attr,
    float* __restrict__ zn, float* __restrict__ protoSum, float* __restrict__ protoCnt,
    int* __restrict__ code, int* __restrict__ validList, int* __restrict__ validCnt)
{
  __shared__ float acc[NPROTO * ND];   // 32 KB per-block segment sums
  __shared__ float red[8];
  __shared__ float cnt[NPROTO];
  __shared__ int codeSh;
  const int t = threadIdx.x;
  for (int i = t; i < NPROTO * ND; i += 512) acc[i] = 0.f;
  if (t < NPROTO) cnt[t] = 0.f;
  __syncthreads();
  const int rowsPer = NB / gridDim.x;
  const int r0 = blockIdx.x * rowsPer;
  for (int rr = 0; rr < rowsPer; ++rr) {
    const int r = r0 + rr;
    const float v = z[(size_t)r * ND + t];
    float s = v * v;
    #pragma unroll
    for (int o = 32; o > 0; o >>= 1) s += __shfl_xor(s, o);
    if ((t & 63) == 0) red[t >> 6] = s;
    if (t == 0) {
      const float* a = attr + (size_t)r * NATTR;
      int c = 0;
      #pragma unroll
      for (int k = 0; k < NATTR; ++k) if (a[k] > 0.5f) c |= 1 << (NATTR - 1 - k);
      codeSh = c;
      code[r] = c;
      cnt[c] += 1.f;
      if (c == NPROTO - 1) { int slot = atomicAdd(validCnt, 1); validList[slot] = r; }
    }
    __syncthreads();
    const float sum = red[0]+red[1]+red[2]+red[3]+red[4]+red[5]+red[6]+red[7];
    const float denom = fmaxf(sqrtf(sum), 1e-12f);   // F.normalize semantics
    const float zv = v / denom;
    zn[(size_t)r * ND + t] = zv;
    acc[codeSh * ND + t] += zv;
    __syncthreads();
  }
  #pragma unroll
  for (int p = 0; p < NPROTO; ++p) atomicAdd(&protoSum[p * ND + t], acc[p * ND + t]);
  if (t < NPROTO) atomicAdd(&protoCnt[t], cnt[t]);
}

// ---------------- K2: normalize prototypes (1 block, 512 thr) --------------
__global__ __launch_bounds__(512) void k_protonorm(
    const float* __restrict__ protoSum, const float* __restrict__ protoCnt,
    float* __restrict__ protos)
{
  __shared__ float red[8];
  const int t = threadIdx.x;
  for (int p = 0; p < NPROTO; ++p) {
    const float c = protoCnt[p];
    const float mean = protoSum[p * ND + t] / fmaxf(c, 1.f);
    float s = mean * mean;
    #pragma unroll
    for (int o = 32; o > 0; o >>= 1) s += __shfl_xor(s, o);
    if ((t & 63) == 0) red[t >> 6] = s;
    __syncthreads();
    const float sum = red[0]+red[1]+red[2]+red[3]+red[4]+red[5]+red[6]+red[7];
    const float pv = (c > 0.f) ? mean / fmaxf(sqrtf(sum), 1e-12f) : 0.f;
    protos[p * ND + t] = pv;
    __syncthreads();
  }
}

// ---------------- K3: prototype contrastive loss ---------------------------
// wave per row; lane = (p = lane&15, d-chunk = lane>>4). Only ~7 cross-lane
// ops per row for the 16-way softmax.
#define PLD (ND + 4)
__global__ __launch_bounds__(256) void k_protoloss(
    const float* __restrict__ zn, const float* __restrict__ protos,
    const int* __restrict__ code, float* __restrict__ protoLossAcc)
{
  __shared__ float pl[NPROTO * PLD];
  const int t = threadIdx.x;
  for (int i = t; i < NPROTO * ND; i += 256)
    pl[(i >> 9) * PLD + (i & 511)] = protos[i];
  __syncthreads();
  const int lane = t & 63, wid = t >> 6;
  const int p = lane & 15, grp = lane >> 4;
  float lacc = 0.f;
  for (int r = blockIdx.x * 4 + wid; r < NB; r += gridDim.x * 4) {
    const float* zr = zn + (size_t)r * ND + grp * 128;
    const int pbase = p * PLD + grp * 128;
    float s = 0.f;
    #pragma unroll
    for (int it = 0; it < 32; ++it) {
      const float4 zv = *(const float4*)(zr + it * 4);
      const float4 pv = *(const float4*)&pl[pbase + it * 4];
      s += zv.x*pv.x + zv.y*pv.y + zv.z*pv.z + zv.w*pv.w;
    }
    s += __shfl_xor(s, 16);
    s += __shfl_xor(s, 32);                 // lane holds sim for p = lane&15
    const float e = expf(s * TINV);
    float alls = e;
    alls += __shfl_xor(alls, 1);
    alls += __shfl_xor(alls, 2);
    alls += __shfl_xor(alls, 4);
    alls += __shfl_xor(alls, 8);            // sum over 16 protos
    const int c = code[r];
    const float pos = __shfl(e, (lane & ~15) | c);
    if (lane == 0) lacc += -logf(pos / fmaxf(alls, 1e-8f) + 1e-8f);
  }
  if (lane == 0) atomicAdd(protoLossAcc, lacc);
}

// ---------------- K5: pairwise term — fp32 tiled GEMM + fused exp-sums -----
// tile: 64 valid-i x 128 j, K-chunks of 16, microtile 4x8 per thread.
#define NJT 64
#define ATLD 68
#define BTLD 132
__global__ __launch_bounds__(256) void k_pairwise(
    const float* __restrict__ zn, const int* __restrict__ code,
    const int* __restrict__ validList, const int* __restrict__ validCnt,
    float* __restrict__ sAllG, float* __restrict__ sPosG)
{
  __shared__ float aT[16 * ATLD];
  __shared__ float bT[16 * BTLD];
  __shared__ int rowIdx[64];
  __shared__ int ao[128];
  __shared__ float tileA[64];
  __shared__ float tileP[64];
  const int t = threadIdx.x;
  const int m = validCnt[0];
  const int nIT = (m + 63) >> 6;
  const int items = nIT * NJT;
  const int tx = t & 15, ty = t >> 4;
  const int ia = t >> 2, kqa = t & 3;
  for (int wi = blockIdx.x; wi < items; wi += gridDim.x) {
    const int g = wi / NJT;
    const int jb = (wi - g * NJT) * 128;
    __syncthreads();   // previous item fully done before LDS reuse
    if (t < 64) {
      const int slot = g * 64 + t;
      rowIdx[t] = (slot < m) ? validList[slot] : -1;
      tileA[t] = 0.f; tileP[t] = 0.f;
    }
    if (t < 128) ao[t] = (code[jb + t] == NPROTO - 1) ? 1 : 0;
    float acc[4][8];
    #pragma unroll
    for (int i = 0; i < 4; ++i)
      #pragma unroll
      for (int j = 0; j < 8; ++j) acc[i][j] = 0.f;
    for (int kc = 0; kc < 32; ++kc) {
      const int k0 = kc * 16;
      __syncthreads();
      // stage A (gathered valid rows), transposed into aT[k][i]
      {
        const int row = rowIdx[ia];
        float4 av = make_float4(0.f, 0.f, 0.f, 0.f);
        if (row >= 0) av = *(const float4*)(zn + (size_t)row * ND + k0 + kqa * 4);
        aT[(kqa*4+0)*ATLD + ia] = av.x;
        aT[(kqa*4+1)*ATLD + ia] = av.y;
        aT[(kqa*4+2)*ATLD + ia] = av.z;
        aT[(kqa*4+3)*ATLD + ia] = av.w;
      }
      // stage B, transposed into bT[k][j]
      #pragma unroll
      for (int h = 0; h < 2; ++h) {
        const int f = t + h * 256;
        const int j = f >> 2, kq = f & 3;
        const float4 bv = *(const float4*)(zn + (size_t)(jb + j) * ND + k0 + kq * 4);
        bT[(kq*4+0)*BTLD + j] = bv.x;
        bT[(kq*4+1)*BTLD + j] = bv.y;
        bT[(kq*4+2)*BTLD + j] = bv.z;
        bT[(kq*4+3)*BTLD + j] = bv.w;
      }
      __syncthreads();
      #pragma unroll
      for (int k = 0; k < 16; ++k) {
        const float4 a  = *(const float4*)&aT[k * ATLD + tx * 4];
        const float4 b0 = *(const float4*)&bT[k * BTLD + ty * 8];
        const float4 b1 = *(const float4*)&bT[k * BTLD + ty * 8 + 4];
        const float ar[4] = {a.x, a.y, a.z, a.w};
        const float br[8] = {b0.x, b0.y, b0.z, b0.w, b1.x, b1.y, b1.z, b1.w};
        #pragma unroll
        for (int i = 0; i < 4; ++i)
          #pragma unroll
          for (int j = 0; j < 8; ++j)
            acc[i][j] = fmaf(ar[i], br[j], acc[i][j]);
      }
    }
    // epilogue: exp, mask diagonal, masked sums per i
    #pragma unroll
    for (int i = 0; i < 4; ++i) {
      const int ri = rowIdx[tx * 4 + i];
      float sA = 0.f, sP = 0.f;
      #pragma unroll
      for (int j = 0; j < 8; ++j) {
        const int jg = jb + ty * 8 + j;
        const float e = expf(acc[i][j] * TINV);
        const float ev = (jg == ri) ? 0.f : e;
        sA += ev;
        if (ao[ty * 8 + j]) sP += ev;
      }
      atomicAdd(&tileA[tx * 4 + i], sA);
      atomicAdd(&tileP[tx * 4 + i], sP);
    }
    __syncthreads();
    if (t < 64) {
      const int slot = g * 64 + t;
      if (slot < m) {
        atomicAdd(&sAllG[slot], tileA[t]);
        atomicAdd(&sPosG[slot], tileP[t]);
      }
    }
  }
}

// ---------------- K6: finalize ---------------------------------------------
__global__ __launch_bounds__(512) void k_final(
    const float* __restrict__ sAllG, const float* __restrict__ sPosG,
    const float* __restrict__ protoLossAcc, const int* __restrict__ validCnt,
    float* __restrict__ out)
{
  __shared__ float red[8];
  const int t = threadIdx.x;
  const int m = validCnt[0];
  const int nvalid = (m >= 2) ? m : 0;   // each all-ones row needs >=1 other
  float s = 0.f;
  for (int i = t; i < nvalid; i += 512)
    s += -logf(sPosG[i] / (sAllG[i] + 1e-8f) + 1e-8f);
  #pragma unroll
  for (int o = 32; o > 0; o >>= 1) s += __shfl_xor(s, o);
  if ((t & 63) == 0) red[t >> 6] = s;
  __syncthreads();
  if (t == 0) {
    const float total = red[0]+red[1]+red[2]+red[3]+red[4]+red[5]+red[6]+red[7];
    const float proto = protoLossAcc[0] / (float)NB;
    float loss = proto;
    if (nvalid > 0) loss = 0.7f * proto + 0.3f * (total / (float)nvalid);
    out[0] = loss;
  }
}

extern "C" void kernel_launch(void* const* d_in, const int* in_sizes, int n_in,
                              void* d_out, int out_size, void* d_ws, size_t ws_size,
                              hipStream_t stream) {
  const float* z = (const float*)d_in[0];
  const float* attr = (const float*)d_in[1];
  float* ws = (float*)d_ws;
  float* zn = ws;                                 // NB*ND
  float* protoSum = zn + (size_t)NB * ND;         // NPROTO*ND   } zeroed
  float* protoCnt = protoSum + NPROTO * ND;       // NPROTO      } zeroed
  float* sAllG = protoCnt + NPROTO;               // NB          } zeroed
  float* sPosG = sAllG + NB;                      // NB          } zeroed
  float* protoLossAcc = sPosG + NB;               // 1           } zeroed
  int* validCnt = (int*)(protoLossAcc + 1);       // 1           } zeroed
  int* code = validCnt + 1;                       // NB
  int* validList = code + NB;                     // NB
  // protos after validList
  float* protos = (float*)(validList + NB);       // NPROTO*ND
  const size_t zeroBytes = (size_t)((char*)(validCnt + 1) - (char*)protoSum);
  hipMemsetAsync(protoSum, 0, zeroBytes, stream);
  k_norm_seg<<<dim3(256), dim3(512), 0, stream>>>(z, attr, zn, protoSum, protoCnt,
                                                  code, validList, validCnt);
  k_protonorm<<<dim3(1), dim3(512), 0, stream>>>(protoSum, protoCnt, protos);
  k_protoloss<<<dim3(256), dim3(256), 0, stream>>>(zn, protos, code, protoLossAcc);
  k_pairwise<<<dim3(512), dim3(256), 0, stream>>>(zn, code, validList, validCnt,
                                                  sAllG, sPosG);
  k_final<<<dim3(1), dim3(512), 0, stream>>>(sAllG, sPosG, protoLossAcc, validCnt,
                                             (float*)d_out);
}

// Round 3
// 119.766 us; speedup vs baseline: 1.3454x; 1.3454x over previous
//
#include <hip/hip_runtime.h>
#include <math.h>

#define NB 8192
#define ND 512
#define NPROTO 16
#define TINV 14.285714285714286f   // 1/0.07

typedef short short8 __attribute__((ext_vector_type(8)));
typedef float float4v __attribute__((ext_vector_type(4)));

__device__ __forceinline__ unsigned short f2bf(float f) {
  unsigned u = __builtin_bit_cast(unsigned, f);
  unsigned r = (u + 0x7FFFu + ((u >> 16) & 1u)) >> 16;
  return (unsigned short)r;
}
__device__ __forceinline__ float bflo(unsigned u) {            // low bf16 of packed pair
  return __builtin_bit_cast(float, u << 16);
}
__device__ __forceinline__ float bfhi(unsigned u) {            // high bf16
  return __builtin_bit_cast(float, u & 0xFFFF0000u);
}

// ---- K1: wave-per-row normalize + bf16 store + LDS-atomic segment sums ----
__global__ __launch_bounds__(512) void k_norm(
    const float* __restrict__ z, const float* __restrict__ attr,
    unsigned short* __restrict__ znb, float* __restrict__ protoSum,
    float* __restrict__ protoCnt, int* __restrict__ code,
    int* __restrict__ validList, int* __restrict__ validCnt)
{
  __shared__ float acc[NPROTO * ND];   // 32 KB
  __shared__ float cnt[NPROTO];
  const int t = threadIdx.x, lane = t & 63, wid = t >> 6;
  for (int i = t; i < NPROTO * ND; i += 512) acc[i] = 0.f;
  if (t < NPROTO) cnt[t] = 0.f;
  __syncthreads();
  #pragma unroll
  for (int rr = 0; rr < 4; ++rr) {
    const int r = blockIdx.x * 32 + wid * 4 + rr;
    const float* zr = z + (size_t)r * ND;
    float v[8];
    #pragma unroll
    for (int jj = 0; jj < 8; ++jj) v[jj] = zr[lane + jj * 64];
    float s = 0.f;
    #pragma unroll
    for (int jj = 0; jj < 8; ++jj) s += v[jj] * v[jj];
    #pragma unroll
    for (int o = 32; o > 0; o >>= 1) s += __shfl_xor(s, o);
    const float inv = 1.f / fmaxf(sqrtf(s), 1e-12f);
    const float* a = attr + (size_t)r * 4;
    const int c = (a[0] > 0.5f ? 8 : 0) | (a[1] > 0.5f ? 4 : 0) |
                  (a[2] > 0.5f ? 2 : 0) | (a[3] > 0.5f ? 1 : 0);
    float* accRow = acc + c * ND;
    #pragma unroll
    for (int jj = 0; jj < 8; ++jj) {
      const float zv = v[jj] * inv;
      atomicAdd(&accRow[lane + jj * 64], zv);            // consecutive banks: conflict-free
      znb[(size_t)r * ND + lane + jj * 64] = f2bf(zv);
    }
    if (lane == 0) {
      code[r] = c;
      atomicAdd(&cnt[c], 1.f);
      if (c == NPROTO - 1) { int slot = atomicAdd(validCnt, 1); validList[slot] = r; }
    }
  }
  __syncthreads();
  for (int i = t; i < NPROTO * ND; i += 512) atomicAdd(&protoSum[i], acc[i]);
  if (t < NPROTO) atomicAdd(&protoCnt[t], cnt[t]);
}

// ---- K2: block 0 normalizes prototypes; blocks 1..N gather valid rows -----
__global__ __launch_bounds__(256) void k_finishA(
    const float* __restrict__ protoSum, const float* __restrict__ protoCnt,
    float* __restrict__ protos, const unsigned short* __restrict__ znb,
    const int* __restrict__ validList, const int* __restrict__ validCnt,
    unsigned short* __restrict__ Ab)
{
  const int t = threadIdx.x;
  if (blockIdx.x == 0) {
    __shared__ float red[4];
    for (int p = 0; p < NPROTO; ++p) {
      const float c = protoCnt[p];
      const float invc = 1.f / fmaxf(c, 1.f);
      const float m0 = protoSum[p * ND + t] * invc;
      const float m1 = protoSum[p * ND + t + 256] * invc;
      float s = m0 * m0 + m1 * m1;
      #pragma unroll
      for (int o = 32; o > 0; o >>= 1) s += __shfl_xor(s, o);
      if ((t & 63) == 0) red[t >> 6] = s;
      __syncthreads();
      const float sum = red[0] + red[1] + red[2] + red[3];
      const float scale = (c > 0.f) ? 1.f / fmaxf(sqrtf(sum), 1e-12f) : 0.f;
      protos[p * ND + t] = m0 * scale;
      protos[p * ND + t + 256] = m1 * scale;
      __syncthreads();
    }
  } else {
    const int m = validCnt[0];
    const int mPad = (m + 63) & ~63;
    const int chunks = mPad * 64;                 // 16B chunks (64 per row)
    const uint4 zero4 = make_uint4(0, 0, 0, 0);
    for (int idx = (blockIdx.x - 1) * 256 + t; idx < chunks; idx += (gridDim.x - 1) * 256) {
      const int slot = idx >> 6, ch = idx & 63;
      uint4 v = zero4;
      if (slot < m) v = ((const uint4*)(znb + (size_t)validList[slot] * ND))[ch];
      ((uint4*)(Ab + (size_t)slot * ND))[ch] = v;
    }
  }
}

// ---- K3: prototype contrastive loss (bf16 reads) --------------------------
#define PLD (ND + 4)
__global__ __launch_bounds__(256) void k_protoloss(
    const unsigned short* __restrict__ znb, const float* __restrict__ protos,
    const int* __restrict__ code, float* __restrict__ protoLossAcc)
{
  __shared__ float pl[NPROTO * PLD];
  const int t = threadIdx.x;
  for (int i = t; i < NPROTO * ND; i += 256)
    pl[(i >> 9) * PLD + (i & 511)] = protos[i];
  __syncthreads();
  const int lane = t & 63, wid = t >> 6;
  const int p = lane & 15, grp = lane >> 4;
  float lacc = 0.f;
  for (int r = blockIdx.x * 4 + wid; r < NB; r += gridDim.x * 4) {
    const uint4* zr = (const uint4*)(znb + (size_t)r * ND + grp * 128);
    const float* pb = &pl[p * PLD + grp * 128];
    float s = 0.f;
    #pragma unroll
    for (int it = 0; it < 16; ++it) {
      const uint4 u = zr[it];
      const float4 p0 = *(const float4*)(pb + it * 8);
      const float4 p1 = *(const float4*)(pb + it * 8 + 4);
      s += bflo(u.x)*p0.x + bfhi(u.x)*p0.y + bflo(u.y)*p0.z + bfhi(u.y)*p0.w;
      s += bflo(u.z)*p1.x + bfhi(u.z)*p1.y + bflo(u.w)*p1.z + bfhi(u.w)*p1.w;
    }
    s += __shfl_xor(s, 16);
    s += __shfl_xor(s, 32);
    const float e = __expf(s * TINV);
    float alls = e;
    alls += __shfl_xor(alls, 1);
    alls += __shfl_xor(alls, 2);
    alls += __shfl_xor(alls, 4);
    alls += __shfl_xor(alls, 8);
    const int c = code[r];
    const float pos = __shfl(e, (lane & ~15) | c);
    if (lane == 0) lacc += -logf(pos / fmaxf(alls, 1e-8f) + 1e-8f);
  }
  if (lane == 0) atomicAdd(protoLossAcc, lacc);
}

// ---- K4: pairwise term — bf16 MFMA GEMM (valid rows x all rows) -----------
// block tile 64i x 128j, K-chunk 64, 4 waves in 2x2 (each 32i x 64j).
__global__ __launch_bounds__(256) void k_pairwise(
    const unsigned short* __restrict__ Ab, const unsigned short* __restrict__ znb,
    const int* __restrict__ code, const int* __restrict__ validList,
    const int* __restrict__ validCnt,
    float* __restrict__ sAllG, float* __restrict__ sPosG)
{
  __shared__ __align__(16) unsigned short aT[64 * 64];    // 8 KB, swizzled
  __shared__ __align__(16) unsigned short bT[128 * 64];   // 16 KB, swizzled
  __shared__ int rowIdx[64];
  __shared__ unsigned char aoSh[128];
  const int t = threadIdx.x, lane = t & 63, wid = t >> 6;
  const int ww = wid & 1, wv = wid >> 1;
  const int m = validCnt[0];
  const int nIT = (m + 63) >> 6;
  const int items = nIT * 64;
  const int grp = lane >> 4, cl = lane & 15;
  for (int wi = blockIdx.x; wi < items; wi += gridDim.x) {
    const int i0 = (wi >> 6) * 64;
    const int jb = (wi & 63) * 128;
    __syncthreads();
    if (t < 64) rowIdx[t] = (i0 + t < m) ? validList[i0 + t] : -1;
    if (t < 128) aoSh[t] = (code[jb + t] == NPROTO - 1) ? 1 : 0;
    float4v acc[2][4];
    #pragma unroll
    for (int mi = 0; mi < 2; ++mi)
      #pragma unroll
      for (int nj = 0; nj < 4; ++nj) acc[mi][nj] = (float4v)(0.f);
    for (int kc = 0; kc < 8; ++kc) {
      const int k0 = kc * 64;
      __syncthreads();
      {  // stage A: 64 rows x 64 bf16 = 512 x 16B chunks, 2 per thread
        const int ia = t >> 2;
        #pragma unroll
        for (int h = 0; h < 2; ++h) {
          const int kq = (t & 3) + h * 4;     // 0..7
          const uint4 v = *(const uint4*)(Ab + (size_t)(i0 + ia) * ND + k0 + kq * 8);
          *(uint4*)((char*)aT + ia * 128 + ((kq * 16) ^ ((ia & 7) << 4))) = v;
        }
      }
      #pragma unroll
      for (int h = 0; h < 4; ++h) {  // stage B: 128 rows x 64 bf16 = 1024 chunks, 4 per thread
        const int f = t + h * 256;
        const int j = f >> 3, kq = f & 7;
        const uint4 v = *(const uint4*)(znb + (size_t)(jb + j) * ND + k0 + kq * 8);
        *(uint4*)((char*)bT + j * 128 + ((kq * 16) ^ ((j & 7) << 4))) = v;
      }
      __syncthreads();
      #pragma unroll
      for (int ks = 0; ks < 2; ++ks) {
        const int kb = ks * 64 + grp * 16;    // byte offset of this lane's 8 bf16
        short8 af[2], bf[4];
        #pragma unroll
        for (int mi = 0; mi < 2; ++mi) {
          const int rw = wv * 32 + mi * 16 + cl;
          af[mi] = *(const short8*)((char*)aT + rw * 128 + (kb ^ ((rw & 7) << 4)));
        }
        #pragma unroll
        for (int nj = 0; nj < 4; ++nj) {
          const int rw = ww * 64 + nj * 16 + cl;
          bf[nj] = *(const short8*)((char*)bT + rw * 128 + (kb ^ ((rw & 7) << 4)));
        }
        #pragma unroll
        for (int mi = 0; mi < 2; ++mi)
          #pragma unroll
          for (int nj = 0; nj < 4; ++nj)
            acc[mi][nj] = __builtin_amdgcn_mfma_f32_16x16x32_bf16(af[mi], bf[nj], acc[mi][nj], 0, 0, 0);
      }
    }
    // epilogue: exp, diag+pos masks, row sums, atomics
    #pragma unroll
    for (int mi = 0; mi < 2; ++mi) {
      float sA[4] = {0.f, 0.f, 0.f, 0.f}, sP[4] = {0.f, 0.f, 0.f, 0.f};
      int ri[4];
      #pragma unroll
      for (int q = 0; q < 4; ++q) ri[q] = rowIdx[wv * 32 + mi * 16 + grp * 4 + q];
      #pragma unroll
      for (int nj = 0; nj < 4; ++nj) {
        const int jl = ww * 64 + nj * 16 + cl;
        const int jg = jb + jl;
        const float ao = aoSh[jl] ? 1.f : 0.f;
        #pragma unroll
        for (int q = 0; q < 4; ++q) {
          float e = __expf(acc[mi][nj][q] * TINV);
          e = (jg == ri[q]) ? 0.f : e;
          sA[q] += e;
          sP[q] += e * ao;
        }
      }
      #pragma unroll
      for (int q = 0; q < 4; ++q) {
        #pragma unroll
        for (int o = 1; o < 16; o <<= 1) {
          sA[q] += __shfl_xor(sA[q], o);
          sP[q] += __shfl_xor(sP[q], o);
        }
      }
      if (cl == 0) {
        #pragma unroll
        for (int q = 0; q < 4; ++q) {
          const int slot = i0 + wv * 32 + mi * 16 + grp * 4 + q;
          if (slot < m) {
            atomicAdd(&sAllG[slot], sA[q]);
            atomicAdd(&sPosG[slot], sP[q]);
          }
        }
      }
    }
  }
}

// ---- K5: finalize ---------------------------------------------------------
__global__ __launch_bounds__(512) void k_final(
    const float* __restrict__ sAllG, const float* __restrict__ sPosG,
    const float* __restrict__ protoLossAcc, const int* __restrict__ validCnt,
    float* __restrict__ out)
{
  __shared__ float red[8];
  const int t = threadIdx.x;
  const int m = validCnt[0];
  const int nvalid = (m >= 2) ? m : 0;
  float s = 0.f;
  for (int i = t; i < nvalid; i += 512)
    s += -logf(sPosG[i] / (sAllG[i] + 1e-8f) + 1e-8f);
  #pragma unroll
  for (int o = 32; o > 0; o >>= 1) s += __shfl_xor(s, o);
  if ((t & 63) == 0) red[t >> 6] = s;
  __syncthreads();
  if (t == 0) {
    const float total = red[0]+red[1]+red[2]+red[3]+red[4]+red[5]+red[6]+red[7];
    const float proto = protoLossAcc[0] / (float)NB;
    float loss = proto;
    if (nvalid > 0) loss = 0.7f * proto + 0.3f * (total / (float)nvalid);
    out[0] = loss;
  }
}

extern "C" void kernel_launch(void* const* d_in, const int* in_sizes, int n_in,
                              void* d_out, int out_size, void* d_ws, size_t ws_size,
                              hipStream_t stream) {
  const float* z = (const float*)d_in[0];
  const float* attr = (const float*)d_in[1];
  unsigned short* znb = (unsigned short*)d_ws;            // NB*ND bf16 (8 MB)
  unsigned short* Ab  = znb + (size_t)NB * ND;            // NB*ND bf16 (8 MB, gathered)
  float* protoSum = (float*)(Ab + (size_t)NB * ND);       // NPROTO*ND   } zeroed
  float* protoCnt = protoSum + NPROTO * ND;               // NPROTO      } zeroed
  float* sAllG = protoCnt + NPROTO;                       // NB          } zeroed
  float* sPosG = sAllG + NB;                              // NB          } zeroed
  float* protoLossAcc = sPosG + NB;                       // 1           } zeroed
  int* validCnt = (int*)(protoLossAcc + 1);               // 1           } zeroed
  int* code = validCnt + 1;                               // NB
  int* validList = code + NB;                             // NB
  float* protos = (float*)(validList + NB);               // NPROTO*ND
  const size_t zeroBytes = (size_t)((char*)(validCnt + 1) - (char*)protoSum);
  hipMemsetAsync(protoSum, 0, zeroBytes, stream);
  k_norm<<<dim3(256), dim3(512), 0, stream>>>(z, attr, znb, protoSum, protoCnt,
                                              code, validList, validCnt);
  k_finishA<<<dim3(64), dim3(256), 0, stream>>>(protoSum, protoCnt, protos,
                                                znb, validList, validCnt, Ab);
  k_protoloss<<<dim3(256), dim3(256), 0, stream>>>(znb, protos, code, protoLossAcc);
  k_pairwise<<<dim3(512), dim3(256), 0, stream>>>(Ab, znb, code, validList, validCnt,
                                                  sAllG, sPosG);
  k_final<<<dim3(1), dim3(512), 0, stream>>>(sAllG, sPosG, protoLossAcc, validCnt,
                                             (float*)d_out);
}

// Round 4
// 119.134 us; speedup vs baseline: 1.3526x; 1.0053x over previous
//
#include <hip/hip_runtime.h>
#include <math.h>

#define NB 8192
#define ND 512
#define NPROTO 16
#define NBLK 256                   // k_norm grid
#define TINV 14.285714285714286f   // 1/0.07

typedef short short8 __attribute__((ext_vector_type(8)));
typedef float float4v __attribute__((ext_vector_type(4)));

__device__ __forceinline__ unsigned short f2bf(float f) {
  unsigned u = __builtin_bit_cast(unsigned, f);
  unsigned r = (u + 0x7FFFu + ((u >> 16) & 1u)) >> 16;
  return (unsigned short)r;
}
__device__ __forceinline__ float bflo(unsigned u) {
  return __builtin_bit_cast(float, u << 16);
}
__device__ __forceinline__ float bfhi(unsigned u) {
  return __builtin_bit_cast(float, u & 0xFFFF0000u);
}

// ---- K1: wave-per-row normalize + bf16 store + per-block partial sums -----
__global__ __launch_bounds__(512) void k_norm(
    const float* __restrict__ z, const float* __restrict__ attr,
    unsigned short* __restrict__ znb, float* __restrict__ partialSum,
    float* __restrict__ partialCnt, int* __restrict__ code,
    int* __restrict__ validList, int* __restrict__ validCnt)
{
  __shared__ float acc[NPROTO * ND];   // 32 KB
  __shared__ float cnt[NPROTO];
  const int t = threadIdx.x, lane = t & 63, wid = t >> 6;
  for (int i = t; i < NPROTO * ND; i += 512) acc[i] = 0.f;
  if (t < NPROTO) cnt[t] = 0.f;
  __syncthreads();
  #pragma unroll
  for (int rr = 0; rr < 4; ++rr) {
    const int r = blockIdx.x * 32 + wid * 4 + rr;
    const float* zr = z + (size_t)r * ND;
    float v[8];
    #pragma unroll
    for (int jj = 0; jj < 8; ++jj) v[jj] = zr[lane + jj * 64];
    float s = 0.f;
    #pragma unroll
    for (int jj = 0; jj < 8; ++jj) s += v[jj] * v[jj];
    #pragma unroll
    for (int o = 32; o > 0; o >>= 1) s += __shfl_xor(s, o);
    const float inv = 1.f / fmaxf(sqrtf(s), 1e-12f);
    const float* a = attr + (size_t)r * 4;
    const int c = (a[0] > 0.5f ? 8 : 0) | (a[1] > 0.5f ? 4 : 0) |
                  (a[2] > 0.5f ? 2 : 0) | (a[3] > 0.5f ? 1 : 0);
    float* accRow = acc + c * ND;
    #pragma unroll
    for (int jj = 0; jj < 8; ++jj) {
      const float zv = v[jj] * inv;
      atomicAdd(&accRow[lane + jj * 64], zv);        // LDS, consecutive banks
      znb[(size_t)r * ND + lane + jj * 64] = f2bf(zv);
    }
    if (lane == 0) {
      code[r] = c;
      atomicAdd(&cnt[c], 1.f);
      if (c == NPROTO - 1) { int slot = atomicAdd(validCnt, 1); validList[slot] = r; }
    }
  }
  __syncthreads();
  // non-atomic coalesced partial flush
  for (int i = t; i < NPROTO * ND; i += 512)
    partialSum[(size_t)blockIdx.x * (NPROTO * ND) + i] = acc[i];
  if (t < NPROTO) partialCnt[blockIdx.x * NPROTO + t] = cnt[t];
}

// ---- K2: 16 blocks, one per prototype: reduce partials + normalize --------
__global__ __launch_bounds__(256) void k_protonorm(
    const float* __restrict__ partialSum, const float* __restrict__ partialCnt,
    float* __restrict__ protos)
{
  __shared__ float red[4];
  const int t = threadIdx.x, lane = t & 63, wid = t >> 6;
  const int p = blockIdx.x;
  float s0 = 0.f, s1 = 0.f;
  #pragma unroll 8
  for (int b = 0; b < NBLK; ++b) {
    const float* base = partialSum + (size_t)b * (NPROTO * ND) + p * ND;
    s0 += base[t];
    s1 += base[t + 256];
  }
  // count: thread b sums partialCnt[b][p]
  float c = partialCnt[t * NPROTO + p];
  #pragma unroll
  for (int o = 32; o > 0; o >>= 1) c += __shfl_xor(c, o);
  if (lane == 0) red[wid] = c;
  __syncthreads();
  const float cTot = red[0] + red[1] + red[2] + red[3];
  __syncthreads();
  const float invc = 1.f / fmaxf(cTot, 1.f);
  const float m0 = s0 * invc, m1 = s1 * invc;
  float sq = m0 * m0 + m1 * m1;
  #pragma unroll
  for (int o = 32; o > 0; o >>= 1) sq += __shfl_xor(sq, o);
  if (lane == 0) red[wid] = sq;
  __syncthreads();
  const float sum = red[0] + red[1] + red[2] + red[3];
  const float scale = (cTot > 0.f) ? 1.f / fmaxf(sqrtf(sum), 1e-12f) : 0.f;
  protos[p * ND + t] = m0 * scale;
  protos[p * ND + t + 256] = m1 * scale;
}

// ---- K3: prototype contrastive loss (bf16 reads) --------------------------
#define PLD (ND + 4)
__global__ __launch_bounds__(256) void k_protoloss(
    const unsigned short* __restrict__ znb, const float* __restrict__ protos,
    const int* __restrict__ code, float* __restrict__ protoLossAcc)
{
  __shared__ float pl[NPROTO * PLD];
  const int t = threadIdx.x;
  for (int i = t; i < NPROTO * ND; i += 256)
    pl[(i >> 9) * PLD + (i & 511)] = protos[i];
  __syncthreads();
  const int lane = t & 63, wid = t >> 6;
  const int p = lane & 15, grp = lane >> 4;
  float lacc = 0.f;
  for (int r = blockIdx.x * 4 + wid; r < NB; r += gridDim.x * 4) {
    const uint4* zr = (const uint4*)(znb + (size_t)r * ND + grp * 128);
    const float* pb = &pl[p * PLD + grp * 128];
    float s = 0.f;
    #pragma unroll
    for (int it = 0; it < 16; ++it) {
      const uint4 u = zr[it];
      const float4 p0 = *(const float4*)(pb + it * 8);
      const float4 p1 = *(const float4*)(pb + it * 8 + 4);
      s += bflo(u.x)*p0.x + bfhi(u.x)*p0.y + bflo(u.y)*p0.z + bfhi(u.y)*p0.w;
      s += bflo(u.z)*p1.x + bfhi(u.z)*p1.y + bflo(u.w)*p1.z + bfhi(u.w)*p1.w;
    }
    s += __shfl_xor(s, 16);
    s += __shfl_xor(s, 32);
    const float e = __expf(s * TINV);
    float alls = e;
    alls += __shfl_xor(alls, 1);
    alls += __shfl_xor(alls, 2);
    alls += __shfl_xor(alls, 4);
    alls += __shfl_xor(alls, 8);
    const int c = code[r];
    const float pos = __shfl(e, (lane & ~15) | c);
    if (lane == 0) lacc += -logf(pos / fmaxf(alls, 1e-8f) + 1e-8f);
  }
  if (lane == 0) atomicAdd(protoLossAcc, lacc);
}

// ---- K4: pairwise term — bf16 MFMA GEMM (valid rows x all rows) -----------
__global__ __launch_bounds__(256) void k_pairwise(
    const unsigned short* __restrict__ znb,
    const int* __restrict__ code, const int* __restrict__ validList,
    const int* __restrict__ validCnt,
    float* __restrict__ sAllG, float* __restrict__ sPosG)
{
  __shared__ __align__(16) unsigned short aT[64 * 64];    // 8 KB, swizzled
  __shared__ __align__(16) unsigned short bT[128 * 64];   // 16 KB, swizzled
  __shared__ int rowIdx[64];
  __shared__ unsigned char aoSh[128];
  const int t = threadIdx.x, lane = t & 63, wid = t >> 6;
  const int ww = wid & 1, wv = wid >> 1;
  const int m = validCnt[0];
  const int nIT = (m + 63) >> 6;
  const int items = nIT * 64;
  const int grp = lane >> 4, cl = lane & 15;
  for (int wi = blockIdx.x; wi < items; wi += gridDim.x) {
    const int i0 = (wi >> 6) * 64;
    const int jb = (wi & 63) * 128;
    __syncthreads();
    if (t < 64) rowIdx[t] = (i0 + t < m) ? validList[i0 + t] : -1;
    if (t < 128) aoSh[t] = (code[jb + t] == NPROTO - 1) ? 1 : 0;
    float4v acc[2][4];
    #pragma unroll
    for (int mi = 0; mi < 2; ++mi)
      #pragma unroll
      for (int nj = 0; nj < 4; ++nj) acc[mi][nj] = (float4v)(0.f);
    for (int kc = 0; kc < 8; ++kc) {
      const int k0 = kc * 64;
      __syncthreads();
      {  // stage A: gathered via validList (64 rows x 8 chunks, 2/thread)
        const int ia = t >> 2;
        const int ri = rowIdx[ia];
        const int srow = (ri < 0) ? 0 : ri;
        #pragma unroll
        for (int h = 0; h < 2; ++h) {
          const int kq = (t & 3) + h * 4;
          const uint4 v = *(const uint4*)(znb + (size_t)srow * ND + k0 + kq * 8);
          *(uint4*)((char*)aT + ia * 128 + ((kq * 16) ^ ((ia & 7) << 4))) = v;
        }
      }
      #pragma unroll
      for (int h = 0; h < 4; ++h) {  // stage B: 128 rows x 8 chunks, 4/thread
        const int f = t + h * 256;
        const int j = f >> 3, kq = f & 7;
        const uint4 v = *(const uint4*)(znb + (size_t)(jb + j) * ND + k0 + kq * 8);
        *(uint4*)((char*)bT + j * 128 + ((kq * 16) ^ ((j & 7) << 4))) = v;
      }
      __syncthreads();
      #pragma unroll
      for (int ks = 0; ks < 2; ++ks) {
        const int kb = ks * 64 + grp * 16;
        short8 af[2], bf[4];
        #pragma unroll
        for (int mi = 0; mi < 2; ++mi) {
          const int rw = wv * 32 + mi * 16 + cl;
          af[mi] = *(const short8*)((char*)aT + rw * 128 + (kb ^ ((rw & 7) << 4)));
        }
        #pragma unroll
        for (int nj = 0; nj < 4; ++nj) {
          const int rw = ww * 64 + nj * 16 + cl;
          bf[nj] = *(const short8*)((char*)bT + rw * 128 + (kb ^ ((rw & 7) << 4)));
        }
        #pragma unroll
        for (int mi = 0; mi < 2; ++mi)
          #pragma unroll
          for (int nj = 0; nj < 4; ++nj)
            acc[mi][nj] = __builtin_amdgcn_mfma_f32_16x16x32_bf16(af[mi], bf[nj], acc[mi][nj], 0, 0, 0);
      }
    }
    #pragma unroll
    for (int mi = 0; mi < 2; ++mi) {
      float sA[4] = {0.f, 0.f, 0.f, 0.f}, sP[4] = {0.f, 0.f, 0.f, 0.f};
      int ri[4];
      #pragma unroll
      for (int q = 0; q < 4; ++q) ri[q] = rowIdx[wv * 32 + mi * 16 + grp * 4 + q];
      #pragma unroll
      for (int nj = 0; nj < 4; ++nj) {
        const int jl = ww * 64 + nj * 16 + cl;
        const int jg = jb + jl;
        const float ao = aoSh[jl] ? 1.f : 0.f;
        #pragma unroll
        for (int q = 0; q < 4; ++q) {
          float e = __expf(acc[mi][nj][q] * TINV);
          e = (jg == ri[q]) ? 0.f : e;
          sA[q] += e;
          sP[q] += e * ao;
        }
      }
      #pragma unroll
      for (int q = 0; q < 4; ++q) {
        #pragma unroll
        for (int o = 1; o < 16; o <<= 1) {
          sA[q] += __shfl_xor(sA[q], o);
          sP[q] += __shfl_xor(sP[q], o);
        }
      }
      if (cl == 0) {
        #pragma unroll
        for (int q = 0; q < 4; ++q) {
          const int slot = i0 + wv * 32 + mi * 16 + grp * 4 + q;
          if (slot < m) {
            atomicAdd(&sAllG[slot], sA[q]);
            atomicAdd(&sPosG[slot], sP[q]);
          }
        }
      }
    }
  }
}

// ---- K5: finalize ---------------------------------------------------------
__global__ __launch_bounds__(512) void k_final(
    const float* __restrict__ sAllG, const float* __restrict__ sPosG,
    const float* __restrict__ protoLossAcc, const int* __restrict__ validCnt,
    float* __restrict__ out)
{
  __shared__ float red[8];
  const int t = threadIdx.x;
  const int m = validCnt[0];
  const int nvalid = (m >= 2) ? m : 0;
  float s = 0.f;
  for (int i = t; i < nvalid; i += 512)
    s += -logf(sPosG[i] / (sAllG[i] + 1e-8f) + 1e-8f);
  #pragma unroll
  for (int o = 32; o > 0; o >>= 1) s += __shfl_xor(s, o);
  if ((t & 63) == 0) red[t >> 6] = s;
  __syncthreads();
  if (t == 0) {
    const float total = red[0]+red[1]+red[2]+red[3]+red[4]+red[5]+red[6]+red[7];
    const float proto = protoLossAcc[0] / (float)NB;
    float loss = proto;
    if (nvalid > 0) loss = 0.7f * proto + 0.3f * (total / (float)nvalid);
    out[0] = loss;
  }
}

extern "C" void kernel_launch(void* const* d_in, const int* in_sizes, int n_in,
                              void* d_out, int out_size, void* d_ws, size_t ws_size,
                              hipStream_t stream) {
  const float* z = (const float*)d_in[0];
  const float* attr = (const float*)d_in[1];
  unsigned short* znb = (unsigned short*)d_ws;            // NB*ND bf16 (8 MB)
  float* sAllG = (float*)(znb + (size_t)NB * ND);         // NB     } zeroed
  float* sPosG = sAllG + NB;                              // NB     } zeroed
  float* protoLossAcc = sPosG + NB;                       // 1      } zeroed
  int* validCnt = (int*)(protoLossAcc + 1);               // 1      } zeroed
  int* code = validCnt + 1;                               // NB
  int* validList = code + NB;                             // NB
  float* protos = (float*)(validList + NB);               // NPROTO*ND
  float* partialSum = protos + NPROTO * ND;               // NBLK*NPROTO*ND (8 MB)
  float* partialCnt = partialSum + (size_t)NBLK * NPROTO * ND;  // NBLK*NPROTO
  const size_t zeroBytes = (size_t)((char*)(validCnt + 1) - (char*)sAllG);
  hipMemsetAsync(sAllG, 0, zeroBytes, stream);
  k_norm<<<dim3(NBLK), dim3(512), 0, stream>>>(z, attr, znb, partialSum, partialCnt,
                                               code, validList, validCnt);
  k_protonorm<<<dim3(NPROTO), dim3(256), 0, stream>>>(partialSum, partialCnt, protos);
  k_protoloss<<<dim3(256), dim3(256), 0, stream>>>(znb, protos, code, protoLossAcc);
  k_pairwise<<<dim3(512), dim3(256), 0, stream>>>(znb, code, validList, validCnt,
                                                  sAllG, sPosG);
  k_final<<<dim3(1), dim3(512), 0, stream>>>(sAllG, sPosG, protoLossAcc, validCnt,
                                             (float*)d_out);
}